// Round 5
// baseline (128.728 us; speedup 1.0000x reference)
//
#include <hip/hip_runtime.h>
#include <math.h>

#define NA 30
#define ND 435          // NA*(NA-1)/2
#define NI 90           // 3*NA
#define NP 12
#define NPH 6           // perms per half-pass
#define NNB (NA-1)

typedef float v2f __attribute__((ext_vector_type(2)));

struct Pre {
  int   pidx[NP][ND];      // pair permutation: d -> image pair under perm p
  int   pinv[NP][ND];      // inverse pair permutation
  int   sigma[NP][NA];     // atom permutation
  int   sigma_inv[NP][NA];
  int   rowv[ND];
  int   colv[ND];
  int   nbr[NA][NNB];      // the 29 pairs containing atom a
  float rjp[NP][ND];       // R_desc[j][pidx[p][d]]
  float rdj[ND][3];        // R_d_desc[j]
  // gtab[k][p][a]: d | pinv<<9 | pidx<<18 | s1<<27 | (s1==s2h)<<28  (coalesced in a)
  unsigned int gtab[NNB][NP][NA];
  // stab[a][a2][p]: d1 | d2<<9 | code<<18   code: 0=heavy(skip), 1=+, 2=-
  alignas(16) unsigned int stab[NA][NA][NP];
  unsigned int hmask[NA][NA];   // bit p set iff sigma_p(a)==a2
};

__device__ __forceinline__ int pair_index(int x, int y) {
  int hi = max(x, y), lo = min(x, y);
  return hi * (hi - 1) / 2 + lo;
}

// ---- preA: small dependent graph work, single block ----
__global__ void preA_kernel(const int* __restrict__ tpl, Pre* ws) {
  const int tid = threadIdx.x;
  const int nthr = blockDim.x;

  for (int d = tid; d < ND; d += nthr) {
    int a = (int)floorf((1.0f + sqrtf(1.0f + 8.0f * (float)d)) * 0.5f);
    while (a * (a - 1) / 2 > d) --a;
    while ((a + 1) * a / 2 <= d) ++a;
    ws->rowv[d] = a;
    ws->colv[d] = d - a * (a - 1) / 2;
  }
  for (int a = tid; a < NA; a += nthr) {
    int k = 0;
    for (int u = 0; u < NA; ++u)
      if (u != a) ws->nbr[a][k++] = pair_index(a, u);
  }
  for (int idx = tid; idx < NP * ND; idx += nthr) {
    int d = idx / NP, p = idx % NP;          // tpl layout: [d*NP + p]
    ws->pidx[p][d] = tpl[idx] - p * ND;
  }
  __syncthreads();
  for (int idx = tid; idx < NP * ND; idx += nthr) {
    int d = idx / NP, p = idx % NP;
    ws->pinv[p][ws->pidx[p][d]] = d;
  }
  // recover atom permutation sigma_p
  for (int idx = tid; idx < NP * NA; idx += nthr) {
    int p = idx / NA, a = idx % NA;
    int u1 = (a == 0) ? 1 : 0;
    int u2 = (a <= 1) ? 2 : 1;
    int e1 = ws->pidx[p][pair_index(a, u1)];
    int e2 = ws->pidx[p][pair_index(a, u2)];
    int r1 = ws->rowv[e1], c1 = ws->colv[e1];
    int r2 = ws->rowv[e2], c2 = ws->colv[e2];
    int sa = (r1 == r2 || r1 == c2) ? r1 : c1;
    ws->sigma[p][a] = sa;
  }
  __syncthreads();
  for (int idx = tid; idx < NP * NA; idx += nthr) {
    int p = idx / NA, a = idx % NA;
    ws->sigma_inv[p][ws->sigma[p][a]] = a;
  }
  __syncthreads();
  for (int it = tid; it < NA * NA; it += nthr) {
    int a = it / NA, a2 = it % NA;
    unsigned m = 0;
#pragma unroll
    for (int p = 0; p < NP; ++p)
      if (ws->sigma[p][a] == a2) m |= (1u << p);
    ws->hmask[a][a2] = m;
  }
}

// ---- preB: bulk table fills, grid-parallel ----
__global__ void preB_kernel(const float* __restrict__ R_desc,
                            const float* __restrict__ R_d_desc,
                            const int* __restrict__ jptr,
                            Pre* ws) {
  const int gid = blockIdx.x * blockDim.x + threadIdx.x;
  const int gsz = gridDim.x * blockDim.x;
  const int j = *jptr;

  for (int idx = gid; idx < NP * ND; idx += gsz) {
    int p = idx / ND, d = idx % ND;
    ws->rjp[p][d] = R_desc[(size_t)j * ND + ws->pidx[p][d]];
  }
  for (int idx = gid; idx < ND * 3; idx += gsz)
    ((float*)ws->rdj)[idx] = R_d_desc[(size_t)j * (ND * 3) + idx];

  for (int idx = gid; idx < NNB * NP * NA; idx += gsz) {
    int a = idx % NA;
    int r = idx / NA;
    int p = r % NP, k = r / NP;
    int d  = ws->nbr[a][k];
    int di = ws->pinv[p][d];
    int d2 = ws->pidx[p][d];
    int s1 = (ws->rowv[d] == a) ? 1 : 0;
    int s2 = (ws->rowv[d2] == ws->sigma[p][a]) ? 1 : 0;
    unsigned int u = (unsigned)d | ((unsigned)di << 9) | ((unsigned)d2 << 18);
    if (s1) u |= (1u << 27);
    if (s1 == s2) u |= (1u << 28);
    ws->gtab[k][p][a] = u;
  }
  for (int idx = gid; idx < NA * NA * NP; idx += gsz) {
    int p = idx % NP;
    int r = idx / NP;
    int a2 = r % NA, a = r / NA;
    unsigned int u = 0;
    if (ws->sigma[p][a] != a2) {
      int uu = ws->sigma_inv[p][a2];
      int d1 = pair_index(a, uu);
      int d2 = ws->pidx[p][d1];
      int s1 = (ws->rowv[d1] == a) ? 1 : 0;
      int s2 = (ws->rowv[d2] == a2) ? 1 : 0;
      unsigned code = (s1 == s2) ? 1u : 2u;
      u = (unsigned)d1 | ((unsigned)d2 << 9) | (code << 18);
    }
    ws->stab[a][a2][p] = u;
  }
}

__global__ __launch_bounds__(256, 4) void gdml_kernel(
    const float* __restrict__ R_desc,
    const float* __restrict__ R_d_desc,
    const Pre* __restrict__ ws,
    float* __restrict__ out) {
  const int n = blockIdx.x;
  const int tid = threadIdx.x;

  __shared__ float  U[NA * NP * 9];    // 12.96 KB: xd (6x435) per half, then Hh overlay
  __shared__ float4 Rdn4[ND];          // 6.96 KB  (xyz = Rdn, w unused)
  __shared__ float4 Rdj4[ND];          // 6.96 KB
  __shared__ float4 v_s4[NP][NA];      // 5.76 KB  (e_p * v, w=0)
  __shared__ float4 w_s4[NP][NA];      // 5.76 KB  (inner)
  __shared__ float dist2[NP];
  __shared__ float e_s[NP], e1_s[NP];
  // total ~38.5 KB -> 4 blocks/CU

  const float q   = 0.22360679774997896f;   // sqrt(5)/10
  const float qq3 = 0.016666666666666666f;  // q*q/3

  // ---- P1: pad-load Rdn/Rdj, zero dist2 ----
  if (tid < NP) dist2[tid] = 0.f;
  for (int idx = tid; idx < ND * 3; idx += 256) {
    int d = idx / 3, c = idx % 3;
    ((float*)&Rdn4[d])[c] = R_d_desc[(size_t)n * (ND * 3) + idx];
    ((float*)&Rdj4[d])[c] = ((const float*)ws->rdj)[idx];
  }
  __syncthreads();

  float h0[9], h1[9];

  auto do_half = [&](int half, float (&h)[9]) {
    float* xd = U;   // [NPH][ND], local perm index
    // fill xd + per-thread dist partials
    float acc[NPH];
#pragma unroll
    for (int pl = 0; pl < NPH; ++pl) acc[pl] = 0.f;
    for (int d = tid; d < ND; d += 256) {
      float rn = R_desc[(size_t)n * ND + d];
#pragma unroll
      for (int pl = 0; pl < NPH; ++pl) {
        int p = half * NPH + pl;
        float x = q * (rn - ws->rjp[p][d]);
        xd[pl * ND + d] = x;
        acc[pl] += x * x;
      }
    }
#pragma unroll
    for (int pl = 0; pl < NPH; ++pl) {
      float a = acc[pl];
      for (int off = 32; off; off >>= 1) a += __shfl_xor(a, off);
      if ((tid & 63) == 0) atomicAdd(&dist2[half * NPH + pl], a);
    }
    __syncthreads();
    if (tid < NPH) {
      int p = half * NPH + tid;
      float dist = sqrtf(dist2[p]);
      float e = expf(-dist) * qq3;
      e_s[p] = e;
      e1_s[p] = e * (1.f + dist);
    }
    __syncthreads();

    // P2': fused v/inner/H per (p,a); H kept in registers
    if (tid < NPH * NA) {
      int a = tid % NA, pl = tid / NA;
      int p = half * NPH + pl;
      const float* xdp = xd + pl * ND;
      v2f V01 = {0.f, 0.f}; float V2 = 0.f;
      v2f I01 = {0.f, 0.f}; float I2 = 0.f;
      v2f H0 = {0.f, 0.f}, H1 = {0.f, 0.f}, H2 = {0.f, 0.f};
      float Hc0 = 0.f, Hc1 = 0.f, Hc2 = 0.f;
      for (int k = 0; k < NNB; ++k) {
        unsigned int u = ws->gtab[k][p][a];
        int d  = u & 511;
        int di = (u >> 9) & 511;
        int d2 = (u >> 18) & 511;
        float s  = (u & (1u << 27)) ? 1.f : -1.f;
        float sg = (u & (1u << 28)) ? 1.f : -1.f;
        float xv = s * xdp[d];
        float xi = s * xdp[di];
        float4 nn = Rdn4[d];
        float4 jd = Rdj4[d];
        float4 jb = Rdj4[d2];
        V01 += (v2f){xv, xv} * (v2f){nn.x, nn.y}; V2 += xv * nn.z;
        I01 += (v2f){xi, xi} * (v2f){jd.x, jd.y}; I2 += xi * jd.z;
        float r0 = sg * nn.x, r1 = sg * nn.y, r2 = sg * nn.z;
        v2f jb01 = {jb.x, jb.y};
        H0 += (v2f){r0, r0} * jb01; Hc0 += r0 * jb.z;
        H1 += (v2f){r1, r1} * jb01; Hc1 += r1 * jb.z;
        H2 += (v2f){r2, r2} * jb01; Hc2 += r2 * jb.z;
      }
      float e = e_s[p];
      v_s4[p][a] = (float4){e * V01.x, e * V01.y, e * V2, 0.f};
      w_s4[p][a] = (float4){I01.x, I01.y, I2, 0.f};
      h[0] = H0.x; h[1] = H0.y; h[2] = Hc0;
      h[3] = H1.x; h[4] = H1.y; h[5] = Hc1;
      h[6] = H2.x; h[7] = H2.y; h[8] = Hc2;
    }
    __syncthreads();   // xd dead -> next half may overwrite U
  };

  do_half(0, h0);
  do_half(1, h1);

  // ---- store heavy blocks into U overlay (xd fully dead) ----
  float* Hh = U;   // [NA][NP*9]
  if (tid < NPH * NA) {
    int a = tid % NA, pl = tid / NA;
#pragma unroll
    for (int r = 0; r < 9; ++r) Hh[a * (NP * 9) + pl * 9 + r] = h0[r];
#pragma unroll
    for (int r = 0; r < 9; ++r) Hh[a * (NP * 9) + (NPH + pl) * 9 + r] = h1[r];
  }
  __syncthreads();

  // ---- P5: fused output, one thread per (a,a2) 3x3 block ----
  float e1r[NP];
#pragma unroll
  for (int p = 0; p < NP; ++p) e1r[p] = e1_s[p];

  float* outn = out + (size_t)n * (NI * NI);
  for (int it = tid; it < NA * NA; it += 256) {
    int a = it / NA, a2 = it % NA;
    v2f A0 = {0.f, 0.f}, A1 = {0.f, 0.f}, A2 = {0.f, 0.f};
    float B0 = 0.f, B1 = 0.f, B2 = 0.f;
    const uint4* st4 = (const uint4*)&ws->stab[a][a2][0];
    uint4 ua = st4[0], ub = st4[1], uc = st4[2];
    unsigned stv[12] = {ua.x, ua.y, ua.z, ua.w, ub.x, ub.y, ub.z, ub.w,
                        uc.x, uc.y, uc.z, uc.w};
#pragma unroll
    for (int p = 0; p < NP; ++p) {
      float4 vv = v_s4[p][a];
      float4 ww = w_s4[p][a2];
      v2f w01 = {ww.x, ww.y};
      A0 += (v2f){vv.x, vv.x} * w01; B0 += vv.x * ww.z;
      A1 += (v2f){vv.y, vv.y} * w01; B1 += vv.y * ww.z;
      A2 += (v2f){vv.z, vv.z} * w01; B2 += vv.z * ww.z;
      unsigned u = stv[p];
      unsigned code = (u >> 18) & 3u;
      float e1 = e1r[p];
      float f = (code == 1u) ? -e1 : ((code == 2u) ? e1 : 0.f);  // minus folded in
      int d1 = u & 511;
      int d2 = (u >> 9) & 511;
      float4 rn1 = Rdn4[d1];
      float4 rj2 = Rdj4[d2];
      float r0 = f * rn1.x, r1 = f * rn1.y, r2 = f * rn1.z;
      v2f j01 = {rj2.x, rj2.y};
      A0 += (v2f){r0, r0} * j01; B0 += r0 * rj2.z;
      A1 += (v2f){r1, r1} * j01; B1 += r1 * rj2.z;
      A2 += (v2f){r2, r2} * j01; B2 += r2 * rj2.z;
    }
    unsigned m = ws->hmask[a][a2];
    while (m) {
      int p = __ffs(m) - 1;
      m &= m - 1;
      float e1 = e1r[p];
      const float* hb = &Hh[a * (NP * 9) + p * 9];
      A0 -= e1 * (v2f){hb[0], hb[1]}; B0 -= e1 * hb[2];
      A1 -= e1 * (v2f){hb[3], hb[4]}; B1 -= e1 * hb[5];
      A2 -= e1 * (v2f){hb[6], hb[7]}; B2 -= e1 * hb[8];
    }
    float* ob = outn + (size_t)(3 * a) * NI + 3 * a2;
    ob[0] = A0.x;          ob[1] = A0.y;          ob[2] = B0;
    ob[NI + 0] = A1.x;     ob[NI + 1] = A1.y;     ob[NI + 2] = B1;
    ob[2 * NI + 0] = A2.x; ob[2 * NI + 1] = A2.y; ob[2 * NI + 2] = B2;
  }
}

extern "C" void kernel_launch(void* const* d_in, const int* in_sizes, int n_in,
                              void* d_out, int out_size, void* d_ws, size_t ws_size,
                              hipStream_t stream) {
  const float* R_desc   = (const float*)d_in[0];
  const float* R_d_desc = (const float*)d_in[1];
  const int*   tpl      = (const int*)d_in[2];
  const int*   jptr     = (const int*)d_in[3];
  float* out = (float*)d_out;
  Pre* ws = (Pre*)d_ws;

  const int n_train = in_sizes[0] / ND;

  hipLaunchKernelGGL(preA_kernel, dim3(1), dim3(256), 0, stream, tpl, ws);
  hipLaunchKernelGGL(preB_kernel, dim3(48), dim3(256), 0, stream,
                     R_desc, R_d_desc, jptr, ws);
  hipLaunchKernelGGL(gdml_kernel, dim3(n_train), dim3(256), 0, stream,
                     R_desc, R_d_desc, ws, out);
}